// Round 1
// baseline (714.548 us; speedup 1.0000x reference)
//
#include <hip/hip_runtime.h>

typedef _Float16 f16;
typedef _Float16 f16x8 __attribute__((ext_vector_type(8)));
typedef float f32x4 __attribute__((ext_vector_type(4)));

// ---------------------------------------------------------------------------
// async 16B global->LDS copy (global_load_lds_dwordx4)
// ---------------------------------------------------------------------------
__device__ __forceinline__ void g2lds16(const void* g, void* l) {
    __builtin_amdgcn_global_load_lds(
        (const __attribute__((address_space(1))) void*)g,
        (__attribute__((address_space(3))) void*)l, 16, 0, 0);
}

// ---------------------------------------------------------------------------
// Pack Wq|Wk|Wv -> f16 Wall[2048][1024], biases -> ball[2048] fp32
// ---------------------------------------------------------------------------
__global__ __launch_bounds__(256)
void prep_w(const float* __restrict__ Wq, const float* __restrict__ bq,
            const float* __restrict__ Wk, const float* __restrict__ bk,
            const float* __restrict__ Wv, const float* __restrict__ bv,
            f16* __restrict__ Wall, float* __restrict__ ball)
{
    const int idx = blockIdx.x * 256 + threadIdx.x;   // 0 .. 2^21-1
    const int o = idx >> 10;
    const int c = idx & 1023;
    float w;
    if (o < 512)        w = Wq[idx];
    else if (o < 1024)  w = Wk[idx - 512 * 1024];
    else                w = Wv[idx - 1024 * 1024];
    Wall[idx] = (f16)w;
    if (c == 0)
        ball[o] = (o < 512) ? bq[o] : (o < 1024) ? bk[o - 512] : bv[o - 1024];
}

// ---------------------------------------------------------------------------
// x [B,C,N] fp32 -> xT [B,N,C] f16   (32x32 LDS tile transpose + cast)
// ---------------------------------------------------------------------------
__global__ __launch_bounds__(256)
void transpose_cast(const float* __restrict__ x, f16* __restrict__ xT)
{
    __shared__ float t[32][33];
    const int b  = blockIdx.z;
    const int c0 = blockIdx.y << 5;
    const int n0 = blockIdx.x << 5;
    const int tx = threadIdx.x & 31, ty = threadIdx.x >> 5;  // ty 0..7
    const float* xb = x + (unsigned long long)b * (1024ull * 1024ull);
#pragma unroll
    for (int i = 0; i < 32; i += 8)
        t[ty + i][tx] = xb[(unsigned long long)(c0 + ty + i) * 1024ull + (n0 + tx)];
    __syncthreads();
    f16* ob = xT + (unsigned long long)b * (1024ull * 1024ull);
#pragma unroll
    for (int i = 0; i < 32; i += 8)
        ob[(unsigned long long)(n0 + ty + i) * 1024ull + (c0 + tx)] = (f16)t[tx][ty + i];
}

// ---------------------------------------------------------------------------
// NT GEMM: C[m,n] = sum_k A[m,k]*B[n,k]  (both row-major, contract last dim)
// 128x128 tile, BK=32, 256 threads = 4 waves in 2x2, 64x64 per wave.
// EPI 0: +bias[n], store f16 (Oh, ldo)
// EPI 1: store fp32 (Of, ldo, batch stride sO)
// EPI 2: += Xres (same layout as output), store fp32
// All dims must divide evenly (they do: M%128==N%128==K%32==0).
// ---------------------------------------------------------------------------
template <int EPI>
__global__ __launch_bounds__(256)
void gemm_nt(const f16* __restrict__ A, const f16* __restrict__ Bm,
             int lda, int ldb, int K,
             unsigned long long sA, unsigned long long sB,
             const float* __restrict__ bias,
             f16* __restrict__ Oh, float* __restrict__ Of,
             int ldo, unsigned long long sO,
             const float* __restrict__ Xres)
{
    __shared__ f16 As[128 * 32];
    __shared__ f16 Bs[128 * 32];

    const int tid  = threadIdx.x;
    const int wave = tid >> 6;
    const int lane = tid & 63;
    const int quad = lane >> 4;
    const int l16  = lane & 15;
    const int wr   = (wave >> 1) << 6;   // wave row offset: 0 / 64
    const int wc   = (wave & 1) << 6;    // wave col offset: 0 / 64

    const int bm = blockIdx.x << 7;
    const int bn = blockIdx.y << 7;
    const int bz = blockIdx.z;

    const f16* Ab = A  + (unsigned long long)bz * sA;
    const f16* Bb = Bm + (unsigned long long)bz * sB;

    // staging: each lane loads 16B; lane -> (row = base+lane/4, col8 = lane%4)
    const int srow = lane >> 2;
    const int scol = (lane & 3) << 3;

    f32x4 acc[4][4] = {};

    for (int k0 = 0; k0 < K; k0 += 32) {
        __syncthreads();
#pragma unroll
        for (int t = 0; t < 2; ++t) {
            const int rbase = t * 64 + wave * 16;   // wave-uniform
            g2lds16(Ab + (unsigned long long)(bm + rbase + srow) * (unsigned long long)lda + (k0 + scol),
                    As + rbase * 32 + lane * 8);
            g2lds16(Bb + (unsigned long long)(bn + rbase + srow) * (unsigned long long)ldb + (k0 + scol),
                    Bs + rbase * 32 + lane * 8);
        }
        __syncthreads();

        f16x8 af[4], bf[4];
#pragma unroll
        for (int i = 0; i < 4; ++i)
            af[i] = *(const f16x8*)(As + (wr + i * 16 + l16) * 32 + quad * 8);
#pragma unroll
        for (int i = 0; i < 4; ++i)
            bf[i] = *(const f16x8*)(Bs + (wc + i * 16 + l16) * 32 + quad * 8);

#pragma unroll
        for (int mi = 0; mi < 4; ++mi)
#pragma unroll
            for (int ni = 0; ni < 4; ++ni)
                acc[mi][ni] = __builtin_amdgcn_mfma_f32_16x16x32_f16(
                    af[mi], bf[ni], acc[mi][ni], 0, 0, 0);
    }

    // epilogue: C/D layout col = lane&15, row = quad*4 + reg  (m89/m91-verified)
#pragma unroll
    for (int mi = 0; mi < 4; ++mi) {
#pragma unroll
        for (int v = 0; v < 4; ++v) {
            const int row = bm + wr + mi * 16 + quad * 4 + v;
#pragma unroll
            for (int ni = 0; ni < 4; ++ni) {
                const int col = bn + wc + ni * 16 + l16;
                float val = acc[mi][ni][v];
                if (EPI == 0) {
                    val += bias[col];
                    Oh[(unsigned long long)row * (unsigned long long)ldo + col] = (f16)val;
                } else if (EPI == 1) {
                    Of[(unsigned long long)bz * sO +
                       (unsigned long long)row * (unsigned long long)ldo + col] = val;
                } else {
                    const unsigned long long off =
                        (unsigned long long)bz * sO +
                        (unsigned long long)row * (unsigned long long)ldo + col;
                    Of[off] = val + Xres[off];
                }
            }
        }
    }
}

// ---------------------------------------------------------------------------
// Row softmax: S [nrows=32768][1024] fp32 -> P f16, one block (256 thr) per row
// ---------------------------------------------------------------------------
__global__ __launch_bounds__(256)
void softmax_rows(const float* __restrict__ S, f16* __restrict__ P)
{
    const unsigned long long row = blockIdx.x;
    const int tid = threadIdx.x;
    const float4 v = ((const float4*)(S + row * 1024ull))[tid];

    float m = fmaxf(fmaxf(v.x, v.y), fmaxf(v.z, v.w));
#pragma unroll
    for (int off = 32; off; off >>= 1)
        m = fmaxf(m, __shfl_xor(m, off, 64));

    __shared__ float redm[4], reds[4];
    const int wave = tid >> 6, lane = tid & 63;
    if (lane == 0) redm[wave] = m;
    __syncthreads();
    m = fmaxf(fmaxf(redm[0], redm[1]), fmaxf(redm[2], redm[3]));

    const float e0 = __expf(v.x - m), e1 = __expf(v.y - m);
    const float e2 = __expf(v.z - m), e3 = __expf(v.w - m);
    float sum = e0 + e1 + e2 + e3;
#pragma unroll
    for (int off = 32; off; off >>= 1)
        sum += __shfl_xor(sum, off, 64);
    if (lane == 0) reds[wave] = sum;
    __syncthreads();
    sum = reds[0] + reds[1] + reds[2] + reds[3];
    const float inv = 1.0f / sum;

    union { f16 h[4]; uint2 u; } pk;
    pk.h[0] = (f16)(e0 * inv); pk.h[1] = (f16)(e1 * inv);
    pk.h[2] = (f16)(e2 * inv); pk.h[3] = (f16)(e3 * inv);
    ((uint2*)(P + row * 1024ull))[tid] = pk.u;
}

// ---------------------------------------------------------------------------
extern "C" void kernel_launch(void* const* d_in, const int* in_sizes, int n_in,
                              void* d_out, int out_size, void* d_ws, size_t ws_size,
                              hipStream_t stream)
{
    const float* x  = (const float*)d_in[0];
    const float* Wq = (const float*)d_in[1];
    const float* bq = (const float*)d_in[2];
    const float* Wk = (const float*)d_in[3];
    const float* bk = (const float*)d_in[4];
    const float* Wv = (const float*)d_in[5];
    const float* bv = (const float*)d_in[6];
    float* out = (float*)d_out;

    // workspace layout (all 16B-aligned, total ~388 MB)
    f16*   xT   = (f16*)d_ws;                               //  64 MB: [32,1024(N),1024(C)]
    f16*   Wall = xT + 32ull * 1024 * 1024;                 //   4 MB: [2048,1024]
    float* ball = (float*)(Wall + 2048ull * 1024);          //   8 KB
    f16*   QKV  = (f16*)(ball + 2048);                      // 128 MB: [32,1024, q|k|v 2048]
    float* S    = (float*)(QKV + 64ull * 1024 * 1024);      // 128 MB: [32,1024,1024]
    f16*   P    = (f16*)(S + 32ull * 1024 * 1024);          //  64 MB: [32,1024,1024]

    prep_w<<<8192, 256, 0, stream>>>(Wq, bq, Wk, bk, Wv, bv, Wall, ball);
    transpose_cast<<<dim3(32, 32, 32), 256, 0, stream>>>(x, xT);

    // QKV projection: [32768,1024] x [2048,1024]^T -> [32768,2048], +bias, f16
    gemm_nt<0><<<dim3(256, 16, 1), 256, 0, stream>>>(
        xT, Wall, 1024, 1024, 1024, 0ull, 0ull,
        ball, QKV, nullptr, 2048, 0ull, nullptr);

    // scores: per batch  q[1024,512] x k'[1024,512]^T -> S fp32
    gemm_nt<1><<<dim3(8, 8, 32), 256, 0, stream>>>(
        QKV, QKV + 512, 2048, 2048, 512,
        1024ull * 2048ull, 1024ull * 2048ull,
        nullptr, nullptr, S, 1024, 1024ull * 1024ull, nullptr);

    softmax_rows<<<32768, 256, 0, stream>>>(S, P);

    // out: per batch  v[1024,1024] x attn[1024,1024]^T  (+x residual) -> fp32
    gemm_nt<2><<<dim3(8, 8, 32), 256, 0, stream>>>(
        QKV + 1024, P, 2048, 1024, 1024,
        1024ull * 2048ull, 1024ull * 1024ull,
        nullptr, nullptr, out, 1024, 1024ull * 1024ull, x);
}

// Round 2
// 644.357 us; speedup vs baseline: 1.1089x; 1.1089x over previous
//
#include <hip/hip_runtime.h>

typedef _Float16 f16;
typedef _Float16 f16x8 __attribute__((ext_vector_type(8)));
typedef float f32x4 __attribute__((ext_vector_type(4)));

// ---------------------------------------------------------------------------
// async 16B global->LDS copy (global_load_lds_dwordx4)
// ---------------------------------------------------------------------------
__device__ __forceinline__ void g2lds16(const void* g, void* l) {
    __builtin_amdgcn_global_load_lds(
        (const __attribute__((address_space(1))) void*)g,
        (__attribute__((address_space(3))) void*)l, 16, 0, 0);
}

// ---------------------------------------------------------------------------
// Pack Wq|Wk|Wv -> f16 Wall[2048][1024], biases -> ball[2048] fp32
// ---------------------------------------------------------------------------
__global__ __launch_bounds__(256)
void prep_w(const float* __restrict__ Wq, const float* __restrict__ bq,
            const float* __restrict__ Wk, const float* __restrict__ bk,
            const float* __restrict__ Wv, const float* __restrict__ bv,
            f16* __restrict__ Wall, float* __restrict__ ball)
{
    const int idx = blockIdx.x * 256 + threadIdx.x;   // 0 .. 2^21-1
    const int o = idx >> 10;
    const int c = idx & 1023;
    float w;
    if (o < 512)        w = Wq[idx];
    else if (o < 1024)  w = Wk[idx - 512 * 1024];
    else                w = Wv[idx - 1024 * 1024];
    Wall[idx] = (f16)w;
    if (c == 0)
        ball[o] = (o < 512) ? bq[o] : (o < 1024) ? bk[o - 512] : bv[o - 1024];
}

// ---------------------------------------------------------------------------
// x [B,C,N] fp32 -> xT [B,N,C] f16   (32x32 LDS tile transpose + cast)
// ---------------------------------------------------------------------------
__global__ __launch_bounds__(256)
void transpose_cast(const float* __restrict__ x, f16* __restrict__ xT)
{
    __shared__ float t[32][33];
    const int b  = blockIdx.z;
    const int c0 = blockIdx.y << 5;
    const int n0 = blockIdx.x << 5;
    const int tx = threadIdx.x & 31, ty = threadIdx.x >> 5;  // ty 0..7
    const float* xb = x + (unsigned long long)b * (1024ull * 1024ull);
#pragma unroll
    for (int i = 0; i < 32; i += 8)
        t[ty + i][tx] = xb[(unsigned long long)(c0 + ty + i) * 1024ull + (n0 + tx)];
    __syncthreads();
    f16* ob = xT + (unsigned long long)b * (1024ull * 1024ull);
#pragma unroll
    for (int i = 0; i < 32; i += 8)
        ob[(unsigned long long)(n0 + ty + i) * 1024ull + (c0 + tx)] = (f16)t[tx][ty + i];
}

// ---------------------------------------------------------------------------
// NT GEMM: C[m,n] = sum_k A[m,k]*B[n,k]  (both row-major, contract last dim)
// 128x128 tile, BK=64 (two 32-halves per barrier pair -> 32 MFMA/barrier),
// 256 threads = 4 waves in 2x2, 64x64 per wave.
// All dims compile-time: LDA/LDB/K/LDO + batch strides SA/SB/SO.
// SWZ=1: grid.x linear, regroup into 8(bm) x 16(bn) supertiles (L2 locality).
// EPI 0: +bias[n], store f16. EPI 1: store fp32. EPI 2: +=Xres, store fp32.
// ---------------------------------------------------------------------------
template <int EPI, int LDA, int LDB, int K, int LDO,
          long long SA, long long SB, long long SO, int SWZ>
__global__ __launch_bounds__(256)
void gemm_nt(const f16* __restrict__ A, const f16* __restrict__ Bm,
             const float* __restrict__ bias,
             f16* __restrict__ Oh, float* __restrict__ Of,
             const float* __restrict__ Xres)
{
    __shared__ f16 As[2 * 128 * 32];   // [kk][row][32]
    __shared__ f16 Bs[2 * 128 * 32];

    const int tid  = threadIdx.x;
    const int wave = tid >> 6;
    const int lane = tid & 63;
    const int quad = lane >> 4;
    const int l16  = lane & 15;
    const int wr   = (wave >> 1) << 6;   // wave row offset: 0 / 64
    const int wc   = (wave & 1) << 6;    // wave col offset: 0 / 64

    int bm, bn;
    if (SWZ) {
        // supertiles of 8 bm x 16 bn: A-chunk 2 MB + B 4 MB stay L2-resident
        const int g = blockIdx.x >> 7;        // 0..31
        const int r = blockIdx.x & 127;
        bm = ((g << 3) | (r & 7)) << 7;
        bn = (r >> 3) << 7;
    } else {
        bm = blockIdx.x << 7;
        bn = blockIdx.y << 7;
    }
    const int bz = blockIdx.z;

    const f16* Ab = A  + (unsigned long long)bz * (unsigned long long)SA;
    const f16* Bb = Bm + (unsigned long long)bz * (unsigned long long)SB;

    // staging: each lane loads 16B; lane -> (row = base+lane/4, col8 = lane%4)
    const int srow = lane >> 2;
    const int scol = (lane & 3) << 3;

    f32x4 acc[4][4] = {};

    for (int k0 = 0; k0 < K; k0 += 64) {
        __syncthreads();
#pragma unroll
        for (int kk = 0; kk < 2; ++kk) {
#pragma unroll
            for (int t = 0; t < 2; ++t) {
                const int rbase = t * 64 + wave * 16;   // wave-uniform
                g2lds16(Ab + (unsigned long long)(bm + rbase + srow) * LDA + (k0 + kk * 32 + scol),
                        As + kk * 4096 + rbase * 32 + lane * 8);
                g2lds16(Bb + (unsigned long long)(bn + rbase + srow) * LDB + (k0 + kk * 32 + scol),
                        Bs + kk * 4096 + rbase * 32 + lane * 8);
            }
        }
        __syncthreads();

#pragma unroll
        for (int kk = 0; kk < 2; ++kk) {
            f16x8 af[4], bf[4];
#pragma unroll
            for (int i = 0; i < 4; ++i)
                af[i] = *(const f16x8*)(As + kk * 4096 + (wr + i * 16 + l16) * 32 + quad * 8);
#pragma unroll
            for (int i = 0; i < 4; ++i)
                bf[i] = *(const f16x8*)(Bs + kk * 4096 + (wc + i * 16 + l16) * 32 + quad * 8);

#pragma unroll
            for (int mi = 0; mi < 4; ++mi)
#pragma unroll
                for (int ni = 0; ni < 4; ++ni)
                    acc[mi][ni] = __builtin_amdgcn_mfma_f32_16x16x32_f16(
                        af[mi], bf[ni], acc[mi][ni], 0, 0, 0);
        }
    }

    // epilogue: C/D layout col = lane&15, row = quad*4 + reg  (m89/m91-verified)
#pragma unroll
    for (int mi = 0; mi < 4; ++mi) {
#pragma unroll
        for (int v = 0; v < 4; ++v) {
            const int row = bm + wr + mi * 16 + quad * 4 + v;
#pragma unroll
            for (int ni = 0; ni < 4; ++ni) {
                const int col = bn + wc + ni * 16 + l16;
                float val = acc[mi][ni][v];
                if (EPI == 0) {
                    val += bias[col];
                    Oh[(unsigned long long)row * LDO + col] = (f16)val;
                } else if (EPI == 1) {
                    Of[(unsigned long long)bz * (unsigned long long)SO +
                       (unsigned long long)row * LDO + col] = val;
                } else {
                    const unsigned long long off =
                        (unsigned long long)bz * (unsigned long long)SO +
                        (unsigned long long)row * LDO + col;
                    Of[off] = val + Xres[off];
                }
            }
        }
    }
}

// ---------------------------------------------------------------------------
// Row softmax: S [nrows=32768][1024] fp32 -> P f16, one block (256 thr) per row
// ---------------------------------------------------------------------------
__global__ __launch_bounds__(256)
void softmax_rows(const float* __restrict__ S, f16* __restrict__ P)
{
    const unsigned long long row = blockIdx.x;
    const int tid = threadIdx.x;
    const float4 v = ((const float4*)(S + row * 1024ull))[tid];

    float m = fmaxf(fmaxf(v.x, v.y), fmaxf(v.z, v.w));
#pragma unroll
    for (int off = 32; off; off >>= 1)
        m = fmaxf(m, __shfl_xor(m, off, 64));

    __shared__ float redm[4], reds[4];
    const int wave = tid >> 6, lane = tid & 63;
    if (lane == 0) redm[wave] = m;
    __syncthreads();
    m = fmaxf(fmaxf(redm[0], redm[1]), fmaxf(redm[2], redm[3]));

    const float e0 = __expf(v.x - m), e1 = __expf(v.y - m);
    const float e2 = __expf(v.z - m), e3 = __expf(v.w - m);
    float sum = e0 + e1 + e2 + e3;
#pragma unroll
    for (int off = 32; off; off >>= 1)
        sum += __shfl_xor(sum, off, 64);
    if (lane == 0) reds[wave] = sum;
    __syncthreads();
    sum = reds[0] + reds[1] + reds[2] + reds[3];
    const float inv = 1.0f / sum;

    union { f16 h[4]; uint2 u; } pk;
    pk.h[0] = (f16)(e0 * inv); pk.h[1] = (f16)(e1 * inv);
    pk.h[2] = (f16)(e2 * inv); pk.h[3] = (f16)(e3 * inv);
    ((uint2*)(P + row * 1024ull))[tid] = pk.u;
}

// ---------------------------------------------------------------------------
extern "C" void kernel_launch(void* const* d_in, const int* in_sizes, int n_in,
                              void* d_out, int out_size, void* d_ws, size_t ws_size,
                              hipStream_t stream)
{
    const float* x  = (const float*)d_in[0];
    const float* Wq = (const float*)d_in[1];
    const float* bq = (const float*)d_in[2];
    const float* Wk = (const float*)d_in[3];
    const float* bk = (const float*)d_in[4];
    const float* Wv = (const float*)d_in[5];
    const float* bv = (const float*)d_in[6];
    float* out = (float*)d_out;

    // workspace layout (all 16B-aligned, total ~388 MB)
    f16*   xT   = (f16*)d_ws;                               //  64 MB: [32,1024(N),1024(C)]
    f16*   Wall = xT + 32ull * 1024 * 1024;                 //   4 MB: [2048,1024]
    float* ball = (float*)(Wall + 2048ull * 1024);          //   8 KB
    f16*   QKV  = (f16*)(ball + 2048);                      // 128 MB: [32,1024, q|k|v 2048]
    float* S    = (float*)(QKV + 64ull * 1024 * 1024);      // 128 MB: [32,1024,1024]
    f16*   P    = (f16*)(S + 32ull * 1024 * 1024);          //  64 MB: [32,1024,1024]

    prep_w<<<8192, 256, 0, stream>>>(Wq, bq, Wk, bk, Wv, bv, Wall, ball);
    transpose_cast<<<dim3(32, 32, 32), 256, 0, stream>>>(x, xT);

    // QKV projection: [32768,1024] x [2048,1024]^T -> [32768,2048], +bias, f16
    gemm_nt<0, 1024, 1024, 1024, 2048, 0ll, 0ll, 0ll, 1>
        <<<dim3(4096, 1, 1), 256, 0, stream>>>(
        xT, Wall, ball, QKV, nullptr, nullptr);

    // scores: per batch  q[1024,512] x k'[1024,512]^T -> S fp32
    gemm_nt<1, 2048, 2048, 512, 1024, 1024ll * 2048, 1024ll * 2048, 1024ll * 1024, 0>
        <<<dim3(8, 8, 32), 256, 0, stream>>>(
        QKV, QKV + 512, nullptr, nullptr, S, nullptr);

    softmax_rows<<<32768, 256, 0, stream>>>(S, P);

    // out: per batch  v[1024,1024] x attn[1024,1024]^T  (+x residual) -> fp32
    gemm_nt<2, 2048, 1024, 1024, 1024, 1024ll * 2048, 1024ll * 1024, 1024ll * 1024, 0>
        <<<dim3(8, 8, 32), 256, 0, stream>>>(
        QKV + 1024, P, nullptr, nullptr, out, x);
}

// Round 3
// 628.151 us; speedup vs baseline: 1.1375x; 1.0258x over previous
//
#include <hip/hip_runtime.h>

typedef _Float16 f16;
typedef _Float16 f16x8 __attribute__((ext_vector_type(8)));
typedef float f32x16 __attribute__((ext_vector_type(16)));

// ---------------------------------------------------------------------------
// async 16B global->LDS copy (global_load_lds_dwordx4)
// LDS side is HW-forced to wave-uniform-base + lane*16 (m104/m108).
// ---------------------------------------------------------------------------
__device__ __forceinline__ void g2lds16(const void* g, void* l) {
    __builtin_amdgcn_global_load_lds(
        (const __attribute__((address_space(1))) void*)g,
        (__attribute__((address_space(3))) void*)l, 16, 0, 0);
}

// ---------------------------------------------------------------------------
// Pack Wq|Wk|Wv -> f16 Wall[2048][1024], biases -> ball[2048] fp32
// ---------------------------------------------------------------------------
__global__ __launch_bounds__(256)
void prep_w(const float* __restrict__ Wq, const float* __restrict__ bq,
            const float* __restrict__ Wk, const float* __restrict__ bk,
            const float* __restrict__ Wv, const float* __restrict__ bv,
            f16* __restrict__ Wall, float* __restrict__ ball)
{
    const int idx = blockIdx.x * 256 + threadIdx.x;   // 0 .. 2^21-1
    const int o = idx >> 10;
    const int c = idx & 1023;
    float w;
    if (o < 512)        w = Wq[idx];
    else if (o < 1024)  w = Wk[idx - 512 * 1024];
    else                w = Wv[idx - 1024 * 1024];
    Wall[idx] = (f16)w;
    if (c == 0)
        ball[o] = (o < 512) ? bq[o] : (o < 1024) ? bk[o - 512] : bv[o - 1024];
}

// ---------------------------------------------------------------------------
// x [B,C,N] fp32 -> xT [B,N,C] f16.  64x64 tile: float4 loads (256B rows),
// f16x8 (16B) stores. LDS pad 65 -> conflict-free.
// ---------------------------------------------------------------------------
__global__ __launch_bounds__(256)
void transpose_cast(const float* __restrict__ x, f16* __restrict__ xT)
{
    __shared__ float t[64][65];
    const int b  = blockIdx.z;
    const int c0 = blockIdx.y << 6;
    const int n0 = blockIdx.x << 6;
    const int tid = threadIdx.x;
    const float* xb = x + (unsigned long long)b * (1024ull * 1024ull);

    {
        const int cl = tid >> 4;          // 0..15
        const int n4 = (tid & 15) << 2;   // 0..60
#pragma unroll
        for (int i = 0; i < 64; i += 16) {
            const float4 v = *(const float4*)(xb + (unsigned long long)(c0 + cl + i) * 1024ull + (n0 + n4));
            t[cl + i][n4 + 0] = v.x; t[cl + i][n4 + 1] = v.y;
            t[cl + i][n4 + 2] = v.z; t[cl + i][n4 + 3] = v.w;
        }
    }
    __syncthreads();
    {
        f16* ob = xT + (unsigned long long)b * (1024ull * 1024ull);
        const int nl = tid >> 3;          // 0..31
        const int c8 = (tid & 7) << 3;    // 0..56
#pragma unroll
        for (int i = 0; i < 64; i += 32) {
            f16x8 h;
#pragma unroll
            for (int j = 0; j < 8; ++j) h[j] = (f16)t[c8 + j][nl + i];
            *(f16x8*)(ob + (unsigned long long)(n0 + nl + i) * 1024ull + (c0 + c8)) = h;
        }
    }
}

// ---------------------------------------------------------------------------
// NT GEMM: C[m,n] = sum_k A[m,k]*B[n,k]  (both row-major, contract last dim)
// 128x128 tile, BK=64, 4 waves 2x2, 64x64/wave, mfma_f32_32x32x16_f16 (2x2).
// LDS: flat [128][64] f16, XOR-swizzled on the GLOBAL address side:
//   lane l stages k-group (l&7)^(l>>3) of row (rb + l>>3)  -> LDS row-major
//   with group g at position g^(row&7). Frag reads then hit 8 distinct
//   bank-quads per 8-lane group -> conflict-free b128.
// SWZ=1 (GEMM1): XCD-pinned supertiles — xcd=bid&7 owns one bn-half (2MB B
//   L2-resident) and streams 8x(8bm x 8bn) sub-supertiles (A-chunk 2MB).
// EPI 0: +bias[n] store f16. EPI 1: store fp32. EPI 2: +=Xres store fp32.
// ---------------------------------------------------------------------------
template <int EPI, int LDA, int LDB, int K, int LDO,
          long long SA, long long SB, long long SO, int SWZ>
__global__ __launch_bounds__(256)
void gemm_nt(const f16* __restrict__ A, const f16* __restrict__ Bm,
             const float* __restrict__ bias,
             f16* __restrict__ Oh, float* __restrict__ Of,
             const float* __restrict__ Xres)
{
    __shared__ f16 As[128 * 64];
    __shared__ f16 Bs[128 * 64];

    const int tid  = threadIdx.x;
    const int wave = tid >> 6;
    const int lane = tid & 63;
    const int l31  = lane & 31;
    const int half = lane >> 5;
    const int wr   = (wave >> 1) << 6;   // wave row offset: 0 / 64
    const int wc   = (wave & 1) << 6;    // wave col offset: 0 / 64

    int bm, bn;
    if (SWZ) {
        const int xcd   = blockIdx.x & 7;
        const int local = blockIdx.x >> 3;    // 0..511
        const int stl   = local >> 6;         // 0..7  sequential per XCD
        const int sub   = local & 63;
        const int st    = stl * 8 + xcd;      // 0..63
        const int bmg   = st >> 1;            // 0..31
        const int bng   = st & 1;             // fixed per XCD (= xcd&1)
        bm = (bmg * 8 + (sub & 7)) << 7;
        bn = (bng * 8 + (sub >> 3)) << 7;
    } else {
        bm = blockIdx.x << 7;
        bn = blockIdx.y << 7;
    }
    const int bz = blockIdx.z;

    const f16* Ab = A  + (unsigned long long)bz * (unsigned long long)SA;
    const f16* Bb = Bm + (unsigned long long)bz * (unsigned long long)SB;

    // staging: lane -> row rb + (l>>3); global k-group XOR-swizzled
    const int srow = lane >> 3;                    // 0..7
    const int scol = (((lane & 7) ^ srow) << 3);   // swizzled f16 col offset

    f32x16 acc[2][2] = {};

    for (int k0 = 0; k0 < K; k0 += 64) {
        __syncthreads();
#pragma unroll
        for (int t = 0; t < 4; ++t) {
            const int rb = t * 32 + wave * 8;     // wave-uniform
            g2lds16(Ab + (unsigned long long)(bm + rb + srow) * LDA + (k0 + scol),
                    As + rb * 64 + lane * 8);
            g2lds16(Bb + (unsigned long long)(bn + rb + srow) * LDB + (k0 + scol),
                    Bs + rb * 64 + lane * 8);
        }
        __syncthreads();

#pragma unroll
        for (int ks = 0; ks < 4; ++ks) {
            const int kg = ks * 2 + half;         // k-group 0..7
            f16x8 af[2], bf[2];
#pragma unroll
            for (int i = 0; i < 2; ++i) {
                const int ra = wr + i * 32 + l31;
                af[i] = *(const f16x8*)(As + ra * 64 + ((kg ^ (ra & 7)) << 3));
                const int rbn = wc + i * 32 + l31;
                bf[i] = *(const f16x8*)(Bs + rbn * 64 + ((kg ^ (rbn & 7)) << 3));
            }
#pragma unroll
            for (int mi = 0; mi < 2; ++mi)
#pragma unroll
                for (int ni = 0; ni < 2; ++ni)
                    acc[mi][ni] = __builtin_amdgcn_mfma_f32_32x32x16_f16(
                        af[mi], bf[ni], acc[mi][ni], 0, 0, 0);
        }
    }

    // epilogue: 32x32 C/D layout col=lane&31, row=(r&3)+8*(r>>2)+4*half
    // (m74/m101-verified, dtype-independent)
#pragma unroll
    for (int mi = 0; mi < 2; ++mi) {
#pragma unroll
        for (int ni = 0; ni < 2; ++ni) {
            const int col = bn + wc + ni * 32 + l31;
            float bc = 0.0f;
            if (EPI == 0) bc = bias[col];
#pragma unroll
            for (int r = 0; r < 16; ++r) {
                const int row = bm + wr + mi * 32 + (r & 3) + 8 * (r >> 2) + 4 * half;
                const float val = acc[mi][ni][r];
                if (EPI == 0) {
                    Oh[(unsigned long long)row * LDO + col] = (f16)(val + bc);
                } else if (EPI == 1) {
                    Of[(unsigned long long)bz * (unsigned long long)SO +
                       (unsigned long long)row * LDO + col] = val;
                } else {
                    const unsigned long long off =
                        (unsigned long long)bz * (unsigned long long)SO +
                        (unsigned long long)row * LDO + col;
                    Of[off] = val + Xres[off];
                }
            }
        }
    }
}

// ---------------------------------------------------------------------------
// Row softmax: S [nrows=32768][1024] fp32 -> P f16, one block (256 thr) per row
// ---------------------------------------------------------------------------
__global__ __launch_bounds__(256)
void softmax_rows(const float* __restrict__ S, f16* __restrict__ P)
{
    const unsigned long long row = blockIdx.x;
    const int tid = threadIdx.x;
    const float4 v = ((const float4*)(S + row * 1024ull))[tid];

    float m = fmaxf(fmaxf(v.x, v.y), fmaxf(v.z, v.w));
#pragma unroll
    for (int off = 32; off; off >>= 1)
        m = fmaxf(m, __shfl_xor(m, off, 64));

    __shared__ float redm[4], reds[4];
    const int wave = tid >> 6, lane = tid & 63;
    if (lane == 0) redm[wave] = m;
    __syncthreads();
    m = fmaxf(fmaxf(redm[0], redm[1]), fmaxf(redm[2], redm[3]));

    const float e0 = __expf(v.x - m), e1 = __expf(v.y - m);
    const float e2 = __expf(v.z - m), e3 = __expf(v.w - m);
    float sum = e0 + e1 + e2 + e3;
#pragma unroll
    for (int off = 32; off; off >>= 1)
        sum += __shfl_xor(sum, off, 64);
    if (lane == 0) reds[wave] = sum;
    __syncthreads();
    sum = reds[0] + reds[1] + reds[2] + reds[3];
    const float inv = 1.0f / sum;

    union { f16 h[4]; uint2 u; } pk;
    pk.h[0] = (f16)(e0 * inv); pk.h[1] = (f16)(e1 * inv);
    pk.h[2] = (f16)(e2 * inv); pk.h[3] = (f16)(e3 * inv);
    ((uint2*)(P + row * 1024ull))[tid] = pk.u;
}

// ---------------------------------------------------------------------------
extern "C" void kernel_launch(void* const* d_in, const int* in_sizes, int n_in,
                              void* d_out, int out_size, void* d_ws, size_t ws_size,
                              hipStream_t stream)
{
    const float* x  = (const float*)d_in[0];
    const float* Wq = (const float*)d_in[1];
    const float* bq = (const float*)d_in[2];
    const float* Wk = (const float*)d_in[3];
    const float* bk = (const float*)d_in[4];
    const float* Wv = (const float*)d_in[5];
    const float* bv = (const float*)d_in[6];
    float* out = (float*)d_out;

    // workspace layout (all 16B-aligned, total ~388 MB)
    f16*   xT   = (f16*)d_ws;                               //  64 MB: [32,1024(N),1024(C)]
    f16*   Wall = xT + 32ull * 1024 * 1024;                 //   4 MB: [2048,1024]
    float* ball = (float*)(Wall + 2048ull * 1024);          //   8 KB
    f16*   QKV  = (f16*)(ball + 2048);                      // 128 MB: [32,1024, q|k|v 2048]
    float* S    = (float*)(QKV + 64ull * 1024 * 1024);      // 128 MB: [32,1024,1024]
    f16*   P    = (f16*)(S + 32ull * 1024 * 1024);          //  64 MB: [32,1024,1024]

    prep_w<<<8192, 256, 0, stream>>>(Wq, bq, Wk, bk, Wv, bv, Wall, ball);
    transpose_cast<<<dim3(16, 16, 32), 256, 0, stream>>>(x, xT);

    // QKV projection: [32768,1024] x [2048,1024]^T -> [32768,2048], +bias, f16
    gemm_nt<0, 1024, 1024, 1024, 2048, 0ll, 0ll, 0ll, 1>
        <<<dim3(4096, 1, 1), 256, 0, stream>>>(
        xT, Wall, ball, QKV, nullptr, nullptr);

    // scores: per batch  q[1024,512] x k'[1024,512]^T -> S fp32
    gemm_nt<1, 2048, 2048, 512, 1024, 1024ll * 2048, 1024ll * 2048, 1024ll * 1024, 0>
        <<<dim3(8, 8, 32), 256, 0, stream>>>(
        QKV, QKV + 512, nullptr, nullptr, S, nullptr);

    softmax_rows<<<32768, 256, 0, stream>>>(S, P);

    // out: per batch  v[1024,1024] x attn[1024,1024]^T  (+x residual) -> fp32
    gemm_nt<2, 2048, 1024, 1024, 1024, 1024ll * 2048, 1024ll * 1024, 1024ll * 1024, 0>
        <<<dim3(8, 8, 32), 256, 0, stream>>>(
        QKV + 1024, P, nullptr, nullptr, out, x);
}

// Round 4
// 610.492 us; speedup vs baseline: 1.1704x; 1.0289x over previous
//
#include <hip/hip_runtime.h>

typedef _Float16 f16;
typedef _Float16 f16x8 __attribute__((ext_vector_type(8)));
typedef float f32x16 __attribute__((ext_vector_type(16)));

// ---------------------------------------------------------------------------
// async 16B global->LDS copy (global_load_lds_dwordx4)
// LDS side is HW-forced to wave-uniform-base + lane*16 (m104/m108).
// ---------------------------------------------------------------------------
__device__ __forceinline__ void g2lds16(const void* g, void* l) {
    __builtin_amdgcn_global_load_lds(
        (const __attribute__((address_space(1))) void*)g,
        (__attribute__((address_space(3))) void*)l, 16, 0, 0);
}

// ---------------------------------------------------------------------------
// Pack Wq|Wk|Wv -> f16 Wall[2048][1024], biases -> ball[2048] fp32
// ---------------------------------------------------------------------------
__global__ __launch_bounds__(256)
void prep_w(const float* __restrict__ Wq, const float* __restrict__ bq,
            const float* __restrict__ Wk, const float* __restrict__ bk,
            const float* __restrict__ Wv, const float* __restrict__ bv,
            f16* __restrict__ Wall, float* __restrict__ ball)
{
    const int idx = blockIdx.x * 256 + threadIdx.x;   // 0 .. 2^21-1
    const int o = idx >> 10;
    const int c = idx & 1023;
    float w;
    if (o < 512)        w = Wq[idx];
    else if (o < 1024)  w = Wk[idx - 512 * 1024];
    else                w = Wv[idx - 1024 * 1024];
    Wall[idx] = (f16)w;
    if (c == 0)
        ball[o] = (o < 512) ? bq[o] : (o < 1024) ? bk[o - 512] : bv[o - 1024];
}

// ---------------------------------------------------------------------------
// x [B,C,N] fp32 -> xT [B,N,C] f16.  64x64 tile: float4 loads (256B rows),
// f16x8 (16B) stores. LDS pad 65 -> conflict-free.
// ---------------------------------------------------------------------------
__global__ __launch_bounds__(256)
void transpose_cast(const float* __restrict__ x, f16* __restrict__ xT)
{
    __shared__ float t[64][65];
    const int b  = blockIdx.z;
    const int c0 = blockIdx.y << 6;
    const int n0 = blockIdx.x << 6;
    const int tid = threadIdx.x;
    const float* xb = x + (unsigned long long)b * (1024ull * 1024ull);

    {
        const int cl = tid >> 4;          // 0..15
        const int n4 = (tid & 15) << 2;   // 0..60
#pragma unroll
        for (int i = 0; i < 64; i += 16) {
            const float4 v = *(const float4*)(xb + (unsigned long long)(c0 + cl + i) * 1024ull + (n0 + n4));
            t[cl + i][n4 + 0] = v.x; t[cl + i][n4 + 1] = v.y;
            t[cl + i][n4 + 2] = v.z; t[cl + i][n4 + 3] = v.w;
        }
    }
    __syncthreads();
    {
        f16* ob = xT + (unsigned long long)b * (1024ull * 1024ull);
        const int nl = tid >> 3;          // 0..31
        const int c8 = (tid & 7) << 3;    // 0..56
#pragma unroll
        for (int i = 0; i < 64; i += 32) {
            f16x8 h;
#pragma unroll
            for (int j = 0; j < 8; ++j) h[j] = (f16)t[c8 + j][nl + i];
            *(f16x8*)(ob + (unsigned long long)(n0 + nl + i) * 1024ull + (c0 + c8)) = h;
        }
    }
}

// ---------------------------------------------------------------------------
// NT GEMM: C[m,n] = sum_k A[m,k]*B[n,k]  (both row-major, contract last dim)
// 128x128 tile, BK=64, 4 waves 2x2, 64x64/wave, mfma_f32_32x32x16_f16 (2x2).
// LDS: flat [128][64] f16, XOR-swizzled on the GLOBAL address side.
// __launch_bounds__(256,4): target 4 waves/SIMD (<=128 unified regs;
//   acc=64 AGPR + <=64 VGPR). If this spills, revert to (256).
// SWZ=1 (GEMM1): XCD-pinned supertiles. Each XCD owns one bn-half
//   (bng = xcd&1, B-half 2MB L2-resident); the 4 XCDs sharing a half split
//   bm via g4 = stl*4 + (xcd>>1). Sub-supertile = 4bm x 8bn -> A-chunk 1MB;
//   1+2=3MB < 4MB per-XCD L2 (R3's 2+2=4MB thrashed: FETCH stayed 145MB).
// EPI 0: +bias[n] store f16. EPI 1: store fp32. EPI 2: +=Xres store fp32.
// ---------------------------------------------------------------------------
template <int EPI, int LDA, int LDB, int K, int LDO,
          long long SA, long long SB, long long SO, int SWZ>
__global__ __launch_bounds__(256, 4)
void gemm_nt(const f16* __restrict__ A, const f16* __restrict__ Bm,
             const float* __restrict__ bias,
             f16* __restrict__ Oh, float* __restrict__ Of,
             const float* __restrict__ Xres)
{
    __shared__ f16 As[128 * 64];
    __shared__ f16 Bs[128 * 64];

    const int tid  = threadIdx.x;
    const int wave = tid >> 6;
    const int lane = tid & 63;
    const int l31  = lane & 31;
    const int half = lane >> 5;
    const int wr   = (wave >> 1) << 6;   // wave row offset: 0 / 64
    const int wc   = (wave & 1) << 6;    // wave col offset: 0 / 64

    int bm, bn;
    if (SWZ) {
        const int xcd   = blockIdx.x & 7;
        const int local = blockIdx.x >> 3;    // 0..511
        const int stl   = local >> 5;         // 0..15 sequential per XCD
        const int sub   = local & 31;
        const int bng   = xcd & 1;            // bn-half owned by this XCD
        const int g4    = stl * 4 + (xcd >> 1);  // 0..63 bm-group-of-4
        bm = (g4 * 4 + (sub & 3)) << 7;
        bn = (bng * 8 + (sub >> 2)) << 7;
    } else {
        bm = blockIdx.x << 7;
        bn = blockIdx.y << 7;
    }
    const int bz = blockIdx.z;

    const f16* Ab = A  + (unsigned long long)bz * (unsigned long long)SA;
    const f16* Bb = Bm + (unsigned long long)bz * (unsigned long long)SB;

    // staging: lane -> row rb + (l>>3); global k-group XOR-swizzled
    const int srow = lane >> 3;                    // 0..7
    const int scol = (((lane & 7) ^ srow) << 3);   // swizzled f16 col offset

    f32x16 acc[2][2] = {};

    for (int k0 = 0; k0 < K; k0 += 64) {
        __syncthreads();
#pragma unroll
        for (int t = 0; t < 4; ++t) {
            const int rb = t * 32 + wave * 8;     // wave-uniform
            g2lds16(Ab + (unsigned long long)(bm + rb + srow) * LDA + (k0 + scol),
                    As + rb * 64 + lane * 8);
            g2lds16(Bb + (unsigned long long)(bn + rb + srow) * LDB + (k0 + scol),
                    Bs + rb * 64 + lane * 8);
        }
        __syncthreads();

#pragma unroll
        for (int ks = 0; ks < 4; ++ks) {
            const int kg = ks * 2 + half;         // k-group 0..7
            f16x8 af[2], bf[2];
#pragma unroll
            for (int i = 0; i < 2; ++i) {
                const int ra = wr + i * 32 + l31;
                af[i] = *(const f16x8*)(As + ra * 64 + ((kg ^ (ra & 7)) << 3));
                const int rbn = wc + i * 32 + l31;
                bf[i] = *(const f16x8*)(Bs + rbn * 64 + ((kg ^ (rbn & 7)) << 3));
            }
#pragma unroll
            for (int mi = 0; mi < 2; ++mi)
#pragma unroll
                for (int ni = 0; ni < 2; ++ni)
                    acc[mi][ni] = __builtin_amdgcn_mfma_f32_32x32x16_f16(
                        af[mi], bf[ni], acc[mi][ni], 0, 0, 0);
        }
    }

    // epilogue: 32x32 C/D layout col=lane&31, row=(r&3)+8*(r>>2)+4*half
    // (m74/m101-verified, dtype-independent)
#pragma unroll
    for (int mi = 0; mi < 2; ++mi) {
#pragma unroll
        for (int ni = 0; ni < 2; ++ni) {
            const int col = bn + wc + ni * 32 + l31;
            float bc = 0.0f;
            if (EPI == 0) bc = bias[col];
#pragma unroll
            for (int r = 0; r < 16; ++r) {
                const int row = bm + wr + mi * 32 + (r & 3) + 8 * (r >> 2) + 4 * half;
                const float val = acc[mi][ni][r];
                if (EPI == 0) {
                    Oh[(unsigned long long)row * LDO + col] = (f16)(val + bc);
                } else if (EPI == 1) {
                    Of[(unsigned long long)bz * (unsigned long long)SO +
                       (unsigned long long)row * LDO + col] = val;
                } else {
                    const unsigned long long off =
                        (unsigned long long)bz * (unsigned long long)SO +
                        (unsigned long long)row * LDO + col;
                    Of[off] = val + Xres[off];
                }
            }
        }
    }
}

// ---------------------------------------------------------------------------
// Row softmax: S [nrows=32768][1024] fp32 -> P f16, one block (256 thr) per row
// ---------------------------------------------------------------------------
__global__ __launch_bounds__(256)
void softmax_rows(const float* __restrict__ S, f16* __restrict__ P)
{
    const unsigned long long row = blockIdx.x;
    const int tid = threadIdx.x;
    const float4 v = ((const float4*)(S + row * 1024ull))[tid];

    float m = fmaxf(fmaxf(v.x, v.y), fmaxf(v.z, v.w));
#pragma unroll
    for (int off = 32; off; off >>= 1)
        m = fmaxf(m, __shfl_xor(m, off, 64));

    __shared__ float redm[4], reds[4];
    const int wave = tid >> 6, lane = tid & 63;
    if (lane == 0) redm[wave] = m;
    __syncthreads();
    m = fmaxf(fmaxf(redm[0], redm[1]), fmaxf(redm[2], redm[3]));

    const float e0 = __expf(v.x - m), e1 = __expf(v.y - m);
    const float e2 = __expf(v.z - m), e3 = __expf(v.w - m);
    float sum = e0 + e1 + e2 + e3;
#pragma unroll
    for (int off = 32; off; off >>= 1)
        sum += __shfl_xor(sum, off, 64);
    if (lane == 0) reds[wave] = sum;
    __syncthreads();
    sum = reds[0] + reds[1] + reds[2] + reds[3];
    const float inv = 1.0f / sum;

    union { f16 h[4]; uint2 u; } pk;
    pk.h[0] = (f16)(e0 * inv); pk.h[1] = (f16)(e1 * inv);
    pk.h[2] = (f16)(e2 * inv); pk.h[3] = (f16)(e3 * inv);
    ((uint2*)(P + row * 1024ull))[tid] = pk.u;
}

// ---------------------------------------------------------------------------
extern "C" void kernel_launch(void* const* d_in, const int* in_sizes, int n_in,
                              void* d_out, int out_size, void* d_ws, size_t ws_size,
                              hipStream_t stream)
{
    const float* x  = (const float*)d_in[0];
    const float* Wq = (const float*)d_in[1];
    const float* bq = (const float*)d_in[2];
    const float* Wk = (const float*)d_in[3];
    const float* bk = (const float*)d_in[4];
    const float* Wv = (const float*)d_in[5];
    const float* bv = (const float*)d_in[6];
    float* out = (float*)d_out;

    // workspace layout (all 16B-aligned, total ~388 MB)
    f16*   xT   = (f16*)d_ws;                               //  64 MB: [32,1024(N),1024(C)]
    f16*   Wall = xT + 32ull * 1024 * 1024;                 //   4 MB: [2048,1024]
    float* ball = (float*)(Wall + 2048ull * 1024);          //   8 KB
    f16*   QKV  = (f16*)(ball + 2048);                      // 128 MB: [32,1024, q|k|v 2048]
    float* S    = (float*)(QKV + 64ull * 1024 * 1024);      // 128 MB: [32,1024,1024]
    f16*   P    = (f16*)(S + 32ull * 1024 * 1024);          //  64 MB: [32,1024,1024]

    prep_w<<<8192, 256, 0, stream>>>(Wq, bq, Wk, bk, Wv, bv, Wall, ball);
    transpose_cast<<<dim3(16, 16, 32), 256, 0, stream>>>(x, xT);

    // QKV projection: [32768,1024] x [2048,1024]^T -> [32768,2048], +bias, f16
    gemm_nt<0, 1024, 1024, 1024, 2048, 0ll, 0ll, 0ll, 1>
        <<<dim3(4096, 1, 1), 256, 0, stream>>>(
        xT, Wall, ball, QKV, nullptr, nullptr);

    // scores: per batch  q[1024,512] x k'[1024,512]^T -> S fp32
    gemm_nt<1, 2048, 2048, 512, 1024, 1024ll * 2048, 1024ll * 2048, 1024ll * 1024, 0>
        <<<dim3(8, 8, 32), 256, 0, stream>>>(
        QKV, QKV + 512, nullptr, nullptr, S, nullptr);

    softmax_rows<<<32768, 256, 0, stream>>>(S, P);

    // out: per batch  v[1024,1024] x attn[1024,1024]^T  (+x residual) -> fp32
    gemm_nt<2, 2048, 1024, 1024, 1024, 1024ll * 2048, 1024ll * 1024, 1024ll * 1024, 0>
        <<<dim3(8, 8, 32), 256, 0, stream>>>(
        QKV + 1024, P, nullptr, nullptr, out, x);
}